// Round 14
// baseline (303.875 us; speedup 1.0000x reference)
//
#include <hip/hip_runtime.h>
#include <hip/hip_bf16.h>
#include <cstdint>

using short8   = __attribute__((ext_vector_type(8))) short;
using floatx4  = __attribute__((ext_vector_type(4))) float;
using float2v  = __attribute__((ext_vector_type(2))) float;
using ushort4v = __attribute__((ext_vector_type(4))) unsigned short;

#define DEVI static __device__ __forceinline__

DEVI unsigned short f2bf(float f) {
    union { float f; unsigned u; } v; v.f = f;
    unsigned r = v.u + 0x7FFFu + ((v.u >> 16) & 1u);
    return (unsigned short)(r >> 16);
}

DEVI float bf2f(unsigned short u) {
    union { unsigned u; float f; } v; v.u = (unsigned)u << 16; return v.f;
}

DEVI unsigned cvtpk_bf16(float lo, float hi) {
    unsigned r;
    asm("v_cvt_pk_bf16_f32 %0, %1, %2" : "=v"(r) : "v"(lo), "v"(hi));
    return r;
}

typedef const __attribute__((address_space(1))) unsigned int gas_uint;
typedef __attribute__((address_space(3))) unsigned int las_uint;

DEVI void gload16(const void* g, void* l) {
    __builtin_amdgcn_global_load_lds((gas_uint*)g, (las_uint*)l, 16, 0, 0);
}

DEVI float gelu_f(float x) {
    float z = 0.7978845608028654f * (x + 0.044715f * x * x * x);
    float e = __expf(2.0f * z);
    float t = 1.0f - 2.0f / (e + 1.0f);   // tanh(z), safe at +-inf
    return 0.5f * x * (1.0f + t);
}

// XCD-chunked bijective blockIdx swizzle (T1; grids here are %8==0)
DEVI int xcd_swizzle(int gX) {
    const int nwg = gX * gridDim.y;
    const int orig = blockIdx.y * gX + blockIdx.x;   // hw dispatch order
    if (nwg & 7) return orig;
    return (orig & 7) * (nwg >> 3) + (orig >> 3);
}

// q pre-scale: 0.125 (1/sqrt(64)) * log2(e) so scores land in exp2 domain
#define QSCALE 0.18033688011112042f

// ------- merged prep: 4 weight transposes + LN1, one launch -----------------
// blocks [0,6912): W[K][N] fp32 -> Wt[N][K] bf16, 32x32 tiles
// blocks [6912,8960): LN1 wave-per-row (4 rows/block) fp32 -> bf16
__global__ __launch_bounds__(256)
void prep_all(const float* __restrict__ W0, const float* __restrict__ W1,
              const float* __restrict__ W2, const float* __restrict__ W3,
              unsigned short* __restrict__ T0, unsigned short* __restrict__ T1,
              unsigned short* __restrict__ T2, unsigned short* __restrict__ T3,
              const float* __restrict__ x, const float* __restrict__ g,
              const float* __restrict__ beta, unsigned short* __restrict__ lnout)
{
    __shared__ float tile_s[32][33];
    const int bid = blockIdx.x;

    if (bid >= 6912) {
        // ---- LN1 job ----
        const int row  = (bid - 6912) * 4 + (threadIdx.x >> 6);
        const int lane = threadIdx.x & 63;
        const float* xr = x + (long)row * 768;
        float4 v[3];
        float s = 0.f, sq = 0.f;
#pragma unroll
        for (int j = 0; j < 3; ++j) {
            v[j] = *(const float4*)(xr + (lane + 64 * j) * 4);
            s  += (v[j].x + v[j].y) + (v[j].z + v[j].w);
            sq += (v[j].x * v[j].x + v[j].y * v[j].y) + (v[j].z * v[j].z + v[j].w * v[j].w);
        }
#pragma unroll
        for (int m = 1; m < 64; m <<= 1) {
            s  += __shfl_xor(s, m);
            sq += __shfl_xor(sq, m);
        }
        const float mean = s * (1.0f / 768.0f);
        const float var  = sq * (1.0f / 768.0f) - mean * mean;
        const float rstd = rsqrtf(var + 1e-5f);
        unsigned short* orow = lnout + (long)row * 768;
#pragma unroll
        for (int j = 0; j < 3; ++j) {
            const int c4 = (lane + 64 * j) * 4;
            const float4 gv = *(const float4*)(g + c4);
            const float4 bv = *(const float4*)(beta + c4);
            ushort4v o;
            o[0] = f2bf((v[j].x - mean) * rstd * gv.x + bv.x);
            o[1] = f2bf((v[j].y - mean) * rstd * gv.y + bv.y);
            o[2] = f2bf((v[j].z - mean) * rstd * gv.z + bv.z);
            o[3] = f2bf((v[j].w - mean) * rstd * gv.w + bv.w);
            *(ushort4v*)(orow + c4) = o;
        }
        return;
    }

    // ---- transpose job ----
    const float* W; unsigned short* Wt; int K, N, nx, tile;
    if (bid < 1728)      { W = W0; Wt = T0; K = 768;  N = 2304; nx = 72; tile = bid; }
    else if (bid < 2304) { W = W1; Wt = T1; K = 768;  N = 768;  nx = 24; tile = bid - 1728; }
    else if (bid < 4608) { W = W2; Wt = T2; K = 768;  N = 3072; nx = 96; tile = bid - 2304; }
    else                 { W = W3; Wt = T3; K = 3072; N = 768;  nx = 24; tile = bid - 4608; }
    const int n0 = (tile % nx) * 32, k0 = (tile / nx) * 32;
    const int tx = threadIdx.x & 31, ty = threadIdx.x >> 5;   // ty 0..7
#pragma unroll
    for (int j = 0; j < 4; ++j)
        tile_s[ty + j * 8][tx] = W[(long)(k0 + ty + j * 8) * N + n0 + tx];
    __syncthreads();
#pragma unroll
    for (int j = 0; j < 4; ++j)
        Wt[(long)(n0 + ty + j * 8) * K + k0 + tx] = f2bf(tile_s[tx][ty + j * 8]);
}

// ---------------- LayerNorm over bf16 input (row=768) -> bf16 ---------------
// wave-per-row, 4 rows/block; 12 elems/lane via 3 x ushort4 loads.
__global__ __launch_bounds__(256)
void ln_cast_bf16(const unsigned short* __restrict__ x, const float* __restrict__ g,
                  const float* __restrict__ beta, unsigned short* __restrict__ out)
{
    const int row  = blockIdx.x * 4 + (threadIdx.x >> 6);
    const int lane = threadIdx.x & 63;
    const unsigned short* xr = x + (long)row * 768;

    float v[12];
    float s = 0.f, sq = 0.f;
#pragma unroll
    for (int j = 0; j < 3; ++j) {
        ushort4v u = *(const ushort4v*)(xr + (lane + 64 * j) * 4);
#pragma unroll
        for (int e = 0; e < 4; ++e) {
            const float f = bf2f(u[e]);
            v[j * 4 + e] = f;
            s += f; sq += f * f;
        }
    }
#pragma unroll
    for (int m = 1; m < 64; m <<= 1) {
        s  += __shfl_xor(s, m);
        sq += __shfl_xor(sq, m);
    }
    const float mean = s * (1.0f / 768.0f);
    const float var  = sq * (1.0f / 768.0f) - mean * mean;
    const float rstd = rsqrtf(var + 1e-5f);

    unsigned short* orow = out + (long)row * 768;
#pragma unroll
    for (int j = 0; j < 3; ++j) {
        const int c4 = (lane + 64 * j) * 4;
        const float4 gv = *(const float4*)(g + c4);
        const float4 bv = *(const float4*)(beta + c4);
        ushort4v o;
        o[0] = f2bf((v[j * 4 + 0] - mean) * rstd * gv.x + bv.x);
        o[1] = f2bf((v[j * 4 + 1] - mean) * rstd * gv.y + bv.y);
        o[2] = f2bf((v[j * 4 + 2] - mean) * rstd * gv.z + bv.z);
        o[3] = f2bf((v[j * 4 + 3] - mean) * rstd * gv.w + bv.w);
        *(ushort4v*)(orow + c4) = o;
    }
}

// ---------------- 128x128-tile bf16 MFMA GEMM, templated epilogue -----------
// A [M][K] bf16 row-major, Bt [N][K] bf16 (B transposed), M=8192.
// EPI 0: qkv scatter (+bias) -> ob0=q[B,H,T,D] (pre-scaled by QSCALE),
//        ob1=k[B,H,T,D],
//        ob2=vT[B,H,D,T] with token order scrambled within 32-blocks
//        (pos = 8*((t>>2)&3) + 4*((t>>4)&1) + (t&3)) so attn PV fragments
//        read contiguous 16B. V blocks (nt>=12) transpose the whole tile
//        through the freed 32KB LDS (swizzled) and store coalesced 256B rows.
// EPI 2: +bias, gelu  -> ob0 bf16 [M][N]
template<int EPI>
__global__ __launch_bounds__(256)
void gemm128(const unsigned short* __restrict__ A,
             const unsigned short* __restrict__ Bt,
             const float* __restrict__ bias,
             unsigned short* __restrict__ ob0,
             unsigned short* __restrict__ ob1,
             unsigned short* __restrict__ ob2,
             int K, int N)
{
    const int wg = xcd_swizzle(gridDim.x);
    const int gY = gridDim.y;
    const int mt = wg / gY, nt = wg % gY;
    const int tid = threadIdx.x;
    const int w = tid >> 6, lane = tid & 63;
    const int l16 = lane & 15, lq = lane >> 4;
    const int wm = w >> 1, wn = w & 1;

    __shared__ unsigned short smem2[2][128 * 64];
    unsigned short* As = smem2[0];
    unsigned short* Bs = smem2[1];

    const floatx4 fzero = {0.f, 0.f, 0.f, 0.f};
    floatx4 acc[4][4];
#pragma unroll
    for (int i = 0; i < 4; ++i)
#pragma unroll
        for (int j = 0; j < 4; ++j) acc[i][j] = fzero;

    const char* Abyte = (const char*)A + (long)mt * 128 * K * 2;
    const char* Bbyte = (const char*)Bt + (long)nt * 128 * K * 2;
    const int KT = K >> 6;

    for (int kt = 0; kt < KT; ++kt) {
        const int kbyte = kt * 128;                    // 64 elems * 2B
#pragma unroll
        for (int r4 = 0; r4 < 4; ++r4) {
            int base = (w * 4 + r4) * 1024;
            int loff = base + lane * 16;
            int row  = loff >> 7;                      // 128B per row
            int scb  = (loff & 127) ^ ((row & 7) << 4);
            gload16(Abyte + (long)row * (K * 2) + kbyte + scb, (char*)As + base);
            gload16(Bbyte + (long)row * (K * 2) + kbyte + scb, (char*)Bs + base);
        }
        __syncthreads();
#pragma unroll
        for (int ks = 0; ks < 2; ++ks) {
            const int kb = ks * 64 + lq * 16;
            short8 af[4], bfr[4];
#pragma unroll
            for (int f = 0; f < 4; ++f) {
                int ar = wm * 64 + f * 16 + l16;
                af[f]  = *(const short8*)((const char*)As + ar * 128 + (kb ^ ((ar & 7) << 4)));
                int br = wn * 64 + f * 16 + l16;
                bfr[f] = *(const short8*)((const char*)Bs + br * 128 + (kb ^ ((br & 7) << 4)));
            }
#pragma unroll
            for (int i = 0; i < 4; ++i)
#pragma unroll
                for (int j = 0; j < 4; ++j)
                    acc[i][j] = __builtin_amdgcn_mfma_f32_16x16x32_bf16(af[i], bfr[j], acc[i][j], 0, 0, 0);
        }
        __syncthreads();
    }

    const int col0 = nt * 128 + wn * 64;
    const int row0 = mt * 128 + wm * 64;

    if (EPI == 0 && nt >= 12) {
        // ---- V tile: LDS transpose (swizzled) then coalesced 256B stores ---
        char* vt_lds = (char*)smem2;     // [dl 128][t 128] bf16 = 32KB
#pragma unroll
        for (int j = 0; j < 4; ++j) {
            const int col = col0 + j * 16 + l16;
            const float bv = bias[col];
            const int dl = wn * 64 + j * 16 + l16;
            const int swz = (dl & 7) << 4;
#pragma unroll
            for (int i = 0; i < 4; ++i) {
                const int tl = wm * 64 + i * 16 + lq * 4;       // t&3 == 0
                const int tS = (tl & ~31) + ((tl & 12) << 1) + ((tl & 16) >> 2);
                ushort4v pk;
#pragma unroll
                for (int r = 0; r < 4; ++r) pk[r] = f2bf(acc[i][j][r] + bv);
                *(ushort4v*)(vt_lds + (dl * 256 + ((tS * 2) ^ swz))) = pk;
            }
        }
        __syncthreads();
        const int bb = mt >> 4;
        const int t0 = (mt & 15) * 128;
        const int hh0 = nt * 2 - 24;
#pragma unroll
        for (int it = 0; it < 8; ++it) {
            const int dl = it * 16 + (tid >> 4);
            const int off = (tid & 15) * 16;
            short8 val = *(const short8*)(vt_lds + (dl * 256 + (off ^ ((dl & 7) << 4))));
            const int hh = hh0 + (dl >> 6), d = dl & 63;
            long base = ((long)(bb * 12 + hh) * 64 + d) * 2048 + t0 + (off >> 1);
            *(short8*)(ob2 + base) = val;
        }
        return;
    }

#pragma unroll
    for (int j = 0; j < 4; ++j) {
        const int col = col0 + j * 16 + l16;
        const float bv = bias[col];
#pragma unroll
        for (int i = 0; i < 4; ++i) {
            const int rowb = row0 + i * 16 + lq * 4;   // 4 consecutive rows
            float v[4];
#pragma unroll
            for (int r = 0; r < 4; ++r) v[r] = acc[i][j][r] + bv;

            if (EPI == 0) {
                // q/k path only (v handled above)
                const int which = (col >= 768) ? 1 : 0;
                const int c = col - which * 768;
                const int hh = c >> 6, d = c & 63;
                const int bb = rowb >> 11;
                const int t  = rowb & 2047;
                unsigned short* dst = (which == 0) ? ob0 : ob1;
                const float qs = (which == 0) ? QSCALE : 1.0f;
                long base = ((long)(bb * 12 + hh) * 2048 + t) * 64 + d;
#pragma unroll
                for (int r = 0; r < 4; ++r) dst[base + (long)r * 64] = f2bf(v[r] * qs);
            } else {  // EPI == 2
#pragma unroll
                for (int r = 0; r < 4; ++r) {
                    long idx = (long)(rowb + r) * N + col;
                    ob0[idx] = f2bf(gelu_f(v[r]));
                }
            }
        }
    }
}

// ---------------- 128x64-tile bf16 MFMA GEMM (narrow-N: proj / out) ---------
// EPI 0: +bias + fp32 resid -> bf16 obf   (attn sublayer: res1 = x + proj)
// EPI 1: +bias + bf16 resid -> fp32 of    (final: out = res1 + mlp)
template<int EPI>
__global__ __launch_bounds__(256)
void gemm_n64(const unsigned short* __restrict__ A,
              const unsigned short* __restrict__ Bt,
              const float* __restrict__ bias,
              const float* __restrict__ residF,
              const unsigned short* __restrict__ residB,
              unsigned short* __restrict__ obf,
              float* __restrict__ of,
              int K, int N)
{
    const int wg = xcd_swizzle(gridDim.x);
    const int gY = gridDim.y;
    const int mt = wg / gY, nt = wg % gY;
    const int tid = threadIdx.x;
    const int w = tid >> 6, lane = tid & 63;
    const int l16 = lane & 15, lq = lane >> 4;
    const int wm = w >> 1, wn = w & 1;

    __shared__ unsigned short As[128 * 64];
    __shared__ unsigned short Bs[64 * 64];

    const floatx4 fzero = {0.f, 0.f, 0.f, 0.f};
    floatx4 acc[4][2];
#pragma unroll
    for (int i = 0; i < 4; ++i)
#pragma unroll
        for (int j = 0; j < 2; ++j) acc[i][j] = fzero;

    const int K2 = K * 2;
    const char* Abyte = (const char*)A + (long)mt * 128 * K2;
    const char* Bbyte = (const char*)Bt + (long)nt * 64 * K2;
    const int KT = K >> 6;

    for (int kt = 0; kt < KT; ++kt) {
        const int kbyte = kt * 128;                    // 64 elems * 2B
#pragma unroll
        for (int r4 = 0; r4 < 4; ++r4) {
            int base = (w * 4 + r4) * 1024;
            int loff = base + lane * 16;
            int row  = loff >> 7;
            int scb  = (loff & 127) ^ ((row & 7) << 4);
            gload16(Abyte + (long)row * K2 + kbyte + scb, (char*)As + base);
        }
#pragma unroll
        for (int r2 = 0; r2 < 2; ++r2) {
            int base = (w * 2 + r2) * 1024;
            int loff = base + lane * 16;
            int row  = loff >> 7;
            int scb  = (loff & 127) ^ ((row & 7) << 4);
            gload16(Bbyte + (long)row * K2 + kbyte + scb, (char*)Bs + base);
        }
        __syncthreads();
#pragma unroll
        for (int ks = 0; ks < 2; ++ks) {
            const int kb = ks * 64 + lq * 16;
            short8 af[4], bfr[2];
#pragma unroll
            for (int f = 0; f < 4; ++f) {
                int ar = wm * 64 + f * 16 + l16;
                af[f] = *(const short8*)((const char*)As + ar * 128 + (kb ^ ((ar & 7) << 4)));
            }
#pragma unroll
            for (int f = 0; f < 2; ++f) {
                int br = wn * 32 + f * 16 + l16;
                bfr[f] = *(const short8*)((const char*)Bs + br * 128 + (kb ^ ((br & 7) << 4)));
            }
#pragma unroll
            for (int i = 0; i < 4; ++i)
#pragma unroll
                for (int j = 0; j < 2; ++j)
                    acc[i][j] = __builtin_amdgcn_mfma_f32_16x16x32_bf16(af[i], bfr[j], acc[i][j], 0, 0, 0);
        }
        __syncthreads();
    }

    const int col0 = nt * 64 + wn * 32;
    const int row0 = mt * 128 + wm * 64;
#pragma unroll
    for (int j = 0; j < 2; ++j) {
        const int col = col0 + j * 16 + l16;
        const float bv = bias[col];
#pragma unroll
        for (int i = 0; i < 4; ++i) {
            const int rowb = row0 + i * 16 + lq * 4;
#pragma unroll
            for (int r = 0; r < 4; ++r) {
                long idx = (long)(rowb + r) * N + col;
                if (EPI == 0)
                    obf[idx] = f2bf(acc[i][j][r] + bv + residF[idx]);
                else
                    of[idx] = acc[i][j][r] + bv + bf2f(residB[idx]);
            }
        }
    }
}

// ---------------- flash attention fwd: 8 waves, 128 q-rows per block --------
// q,k: bf16 [B*H, 2048, 64] (q pre-scaled); vt: bf16 [B*H, 64, 2048]
// (32-token scrambled); y: bf16 [B*T, 768]. r10-proven version (110.0 us).
__global__ __launch_bounds__(512)
void attn_fwd(const unsigned short* __restrict__ q,
              const unsigned short* __restrict__ k,
              const unsigned short* __restrict__ vt,
              const float* __restrict__ mask,
              unsigned short* __restrict__ y)
{
    const int qt = blockIdx.x;     // 0..15 (128 q rows each)
    const int bh = blockIdx.y;     // 0..47
    const int b = bh / 12, h = bh - b * 12;
    const int tid = threadIdx.x;   // 0..511
    const int w = tid >> 6, lane = tid & 63;
    const int l16 = lane & 15, lq = lane >> 4;

    __shared__ unsigned short Ks[128 * 64];
    __shared__ unsigned short Vs[64 * 128];
    __shared__ float madd[128];
    __shared__ int mq;

    if (tid == 0) mq = 0;
    __syncthreads();
    {
        const float* mrow = mask + (long)b * 2048 + tid * 4;
        int bad = 0;
#pragma unroll
        for (int j = 0; j < 4; ++j) bad |= (mrow[j] != 1.0f);
        if (bad) atomicOr(&mq, 1);
    }

    // Q fragments in registers (B operand of swapped QK^T)
    const unsigned short* qrow = q + ((long)bh * 2048 + qt * 128 + w * 16 + l16) * 64;
    const short8 qf0 = *(const short8*)(qrow + lq * 8);
    const short8 qf1 = *(const short8*)(qrow + 32 + lq * 8);

    // hoisted per-thread staging offsets (512 threads x 16B x 2 passes each)
    const char* kg = (const char*)(k + (long)bh * 2048 * 64);
    const char* vg = (const char*)(vt + (long)bh * 64 * 2048);
    int koff[2], voff[2], lb[2];
#pragma unroll
    for (int r2 = 0; r2 < 2; ++r2) {
        int loff = r2 * 8192 + tid * 16;          // 0..16383
        int rowK = loff >> 7;
        koff[r2] = rowK * 128 + ((loff & 127) ^ ((rowK & 7) << 4));
        int rowV = loff >> 8;
        voff[r2] = rowV * 4096 + ((loff & 255) ^ ((rowV & 7) << 4));
        lb[r2]   = loff;
    }

    __syncthreads();
    const bool usemask = (mq != 0);

    const floatx4 fzero = {0.f, 0.f, 0.f, 0.f};
    floatx4 accO[4];
#pragma unroll
    for (int n = 0; n < 4; ++n) accO[n] = fzero;
    float m2 = -1e30f, lsum = 0.f;

    for (int kt = 0; kt < 16; ++kt) {
        const char* kgt = kg + (long)kt * 16384;   // 128 rows * 128B
        const char* vgt = vg + kt * 256;           // 128 cols * 2B
#pragma unroll
        for (int r2 = 0; r2 < 2; ++r2) {
            gload16(kgt + koff[r2], (char*)Ks + lb[r2]);
            gload16(vgt + voff[r2], (char*)Vs + lb[r2]);
        }
        if (usemask && tid < 128)
            madd[tid] = (1.0f - mask[b * 2048 + kt * 128 + tid]) * (-10000.0f * 1.4426950408889634f);
        __syncthreads();

        // S^T = K Q^T : lane -> S[key=f*16+lq*4+j][q=l16]
        floatx4 st[8];
#pragma unroll
        for (int f = 0; f < 8; ++f) st[f] = fzero;
        __builtin_amdgcn_s_setprio(1);
#pragma unroll
        for (int f = 0; f < 8; ++f) {
            const int kr = f * 16 + l16;
            const int sw = (kr & 7) << 4;
            short8 ka0 = *(const short8*)((const char*)Ks + kr * 128 + ((lq * 16) ^ sw));
            short8 ka1 = *(const short8*)((const char*)Ks + kr * 128 + ((64 + lq * 16) ^ sw));
            st[f] = __builtin_amdgcn_mfma_f32_16x16x32_bf16(ka0, qf0, st[f], 0, 0, 0);
            st[f] = __builtin_amdgcn_mfma_f32_16x16x32_bf16(ka1, qf1, st[f], 0, 0, 0);
        }
        __builtin_amdgcn_s_setprio(0);

        if (usemask) {
#pragma unroll
            for (int f = 0; f < 8; ++f) {
                floatx4 md = *(const floatx4*)((const char*)madd + f * 64 + lq * 16);
                st[f] += md;
            }
        }

        // split S into float2 halves (packed-math friendly)
        float2v lo[8], hi[8];
#pragma unroll
        for (int f = 0; f < 8; ++f) {
            lo[f][0] = st[f][0]; lo[f][1] = st[f][1];
            hi[f][0] = st[f][2]; hi[f][1] = st[f][3];
        }

        // row max: packed pairwise tree + cross-lq reduce
        float2v mx = __builtin_elementwise_max(lo[0], hi[0]);
#pragma unroll
        for (int f = 1; f < 8; ++f)
            mx = __builtin_elementwise_max(mx, __builtin_elementwise_max(lo[f], hi[f]));
        float rm = fmaxf(mx[0], mx[1]);
        rm = fmaxf(rm, __shfl_xor(rm, 16));
        rm = fmaxf(rm, __shfl_xor(rm, 32));

        if (!__all(rm <= m2 + 8.0f)) {      // defer-max (T13, THR=8 exp2-domain)
            const float mn = fmaxf(m2, rm);
            const float corr = exp2f(m2 - mn);
            m2 = mn;
            lsum *= corr;
            floatx4 cv;
            cv[0] = __shfl(corr, lq * 4 + 0);
            cv[1] = __shfl(corr, lq * 4 + 1);
            cv[2] = __shfl(corr, lq * 4 + 2);
            cv[3] = __shfl(corr, lq * 4 + 3);
#pragma unroll
            for (int n = 0; n < 4; ++n) accO[n] *= cv;
        }

        // P = exp2(S - m2): packed subtract + packed accumulate, scalar exp2
        const float2v m2v = {m2, m2};
        float2v rs2 = {0.f, 0.f};
        unsigned pw[16];
#pragma unroll
        for (int f = 0; f < 8; ++f) {
            float2v d0 = lo[f] - m2v;
            float2v d1 = hi[f] - m2v;
            float2v e0, e1;
            e0[0] = exp2f(d0[0]); e0[1] = exp2f(d0[1]);
            e1[0] = exp2f(d1[0]); e1[1] = exp2f(d1[1]);
            rs2 += e0;
            rs2 += e1;
            pw[f * 2]     = cvtpk_bf16(e0[0], e0[1]);
            pw[f * 2 + 1] = cvtpk_bf16(e1[0], e1[1]);
        }
        float rs = rs2[0] + rs2[1];
        rs += __shfl_xor(rs, 16);
        rs += __shfl_xor(rs, 32);
        lsum += rs;

        // O += P V  (P packed lane-locally; V tokens pre-scrambled to match)
        __builtin_amdgcn_s_setprio(1);
#pragma unroll
        for (int c = 0; c < 4; ++c) {
            union { unsigned u[4]; short8 s8; } pu;
            pu.u[0] = pw[c * 4 + 0];
            pu.u[1] = pw[c * 4 + 1];
            pu.u[2] = pw[c * 4 + 2];
            pu.u[3] = pw[c * 4 + 3];
            const int kb2 = c * 64 + lq * 16;
#pragma unroll
            for (int n = 0; n < 4; ++n) {
                const int vr = n * 16 + l16;
                short8 vb = *(const short8*)((const char*)Vs + vr * 256 + (kb2 ^ ((vr & 7) << 4)));
                accO[n] = __builtin_amdgcn_mfma_f32_16x16x32_bf16(pu.s8, vb, accO[n], 0, 0, 0);
            }
        }
        __builtin_amdgcn_s_setprio(0);
        __syncthreads();
    }

    const float li = 1.0f / lsum;
    floatx4 lv;
    lv[0] = __shfl(li, lq * 4 + 0);
    lv[1] = __shfl(li, lq * 4 + 1);
    lv[2] = __shfl(li, lq * 4 + 2);
    lv[3] = __shfl(li, lq * 4 + 3);
    unsigned short* ybase = y + ((long)(b * 2048 + qt * 128 + w * 16 + lq * 4)) * 768 + h * 64;
#pragma unroll
    for (int r = 0; r < 4; ++r) {
        unsigned short* yrow = ybase + (long)r * 768;
#pragma unroll
        for (int n = 0; n < 4; ++n)
            yrow[n * 16 + l16] = f2bf(accO[n][r] * lv[r]);
    }
}

// ---------------------------------------------------------------------------
extern "C" void kernel_launch(void* const* d_in, const int* in_sizes, int n_in,
                              void* d_out, int out_size, void* d_ws, size_t ws_size,
                              hipStream_t stream)
{
    const float* x     = (const float*)d_in[0];
    const float* amask = (const float*)d_in[1];
    const float* ln1g  = (const float*)d_in[2];
    const float* ln1b  = (const float*)d_in[3];
    const float* ln2g  = (const float*)d_in[4];
    const float* ln2b  = (const float*)d_in[5];
    const float* Wattn = (const float*)d_in[6];
    const float* battn = (const float*)d_in[7];
    const float* Wproj = (const float*)d_in[8];
    const float* bproj = (const float*)d_in[9];
    const float* Wfc   = (const float*)d_in[10];
    const float* bfc   = (const float*)d_in[11];
    const float* Wout  = (const float*)d_in[12];
    const float* bout  = (const float*)d_in[13];
    float* out = (float*)d_out;

    char* ws = (char*)d_ws;
    unsigned short* wt_attn = (unsigned short*)ws;  ws += (long)2304 * 768 * 2;
    unsigned short* wt_proj = (unsigned short*)ws;  ws += (long)768 * 768 * 2;
    unsigned short* wt_fc   = (unsigned short*)ws;  ws += (long)3072 * 768 * 2;
    unsigned short* wt_out  = (unsigned short*)ws;  ws += (long)768 * 3072 * 2;
    unsigned short* hbuf    = (unsigned short*)ws;  ws += (long)8192 * 768 * 2;
    unsigned short* qbuf    = (unsigned short*)ws;  ws += (long)48 * 2048 * 64 * 2;
    unsigned short* kbuf    = (unsigned short*)ws;  ws += (long)48 * 2048 * 64 * 2;
    unsigned short* vtbuf   = (unsigned short*)ws;  ws += (long)48 * 2048 * 64 * 2;
    unsigned short* ybuf    = (unsigned short*)ws;  ws += (long)8192 * 768 * 2;
    unsigned short* hfc     = (unsigned short*)ws;  ws += (long)8192 * 3072 * 2;
    unsigned short* res1    = (unsigned short*)ws;  ws += (long)8192 * 768 * 2;

    prep_all<<<8960, 256, 0, stream>>>(Wattn, Wproj, Wfc, Wout,
                                       wt_attn, wt_proj, wt_fc, wt_out,
                                       x, ln1g, ln1b, hbuf);

    gemm128<0><<<dim3(64, 18), 256, 0, stream>>>(hbuf, wt_attn, battn,
                                                 qbuf, kbuf, vtbuf, 768, 2304);

    attn_fwd<<<dim3(16, 48), 512, 0, stream>>>(qbuf, kbuf, vtbuf, amask, ybuf);

    // res1 = bf16(x + proj(y))   [attn sublayer output, bf16 residual]
    gemm_n64<0><<<dim3(64, 12), 256, 0, stream>>>(ybuf, wt_proj, bproj,
                                                  x, nullptr, res1, nullptr, 768, 768);

    ln_cast_bf16<<<2048, 256, 0, stream>>>(res1, ln2g, ln2b, hbuf);

    gemm128<2><<<dim3(64, 24), 256, 0, stream>>>(hbuf, wt_fc, bfc,
                                                 hfc, nullptr, nullptr, 768, 3072);

    // out = res1 + mlp(hfc)   [fp32 final output]
    gemm_n64<1><<<dim3(64, 12), 256, 0, stream>>>(hfc, wt_out, bout,
                                                  nullptr, res1, nullptr, out, 3072, 768);
}

// Round 16
// 301.294 us; speedup vs baseline: 1.0086x; 1.0086x over previous
//
#include <hip/hip_runtime.h>
#include <hip/hip_bf16.h>
#include <cstdint>

using short8   = __attribute__((ext_vector_type(8))) short;
using floatx4  = __attribute__((ext_vector_type(4))) float;
using float2v  = __attribute__((ext_vector_type(2))) float;
using ushort4v = __attribute__((ext_vector_type(4))) unsigned short;

#define DEVI static __device__ __forceinline__

DEVI unsigned short f2bf(float f) {
    union { float f; unsigned u; } v; v.f = f;
    unsigned r = v.u + 0x7FFFu + ((v.u >> 16) & 1u);
    return (unsigned short)(r >> 16);
}

DEVI float bf2f(unsigned short u) {
    union { unsigned u; float f; } v; v.u = (unsigned)u << 16; return v.f;
}

DEVI unsigned cvtpk_bf16(float lo, float hi) {
    unsigned r;
    asm("v_cvt_pk_bf16_f32 %0, %1, %2" : "=v"(r) : "v"(lo), "v"(hi));
    return r;
}

typedef const __attribute__((address_space(1))) unsigned int gas_uint;
typedef __attribute__((address_space(3))) unsigned int las_uint;

DEVI void gload16(const void* g, void* l) {
    __builtin_amdgcn_global_load_lds((gas_uint*)g, (las_uint*)l, 16, 0, 0);
}

DEVI float gelu_f(float x) {
    float z = 0.7978845608028654f * (x + 0.044715f * x * x * x);
    float e = __expf(2.0f * z);
    float t = 1.0f - 2.0f / (e + 1.0f);   // tanh(z), safe at +-inf
    return 0.5f * x * (1.0f + t);
}

// XCD-chunked bijective blockIdx swizzle (T1; grids here are %8==0)
DEVI int xcd_swizzle(int gX) {
    const int nwg = gX * gridDim.y;
    const int orig = blockIdx.y * gX + blockIdx.x;   // hw dispatch order
    if (nwg & 7) return orig;
    return (orig & 7) * (nwg >> 3) + (orig >> 3);
}

// q pre-scale: 0.125 (1/sqrt(64)) * log2(e) so scores land in exp2 domain
#define QSCALE 0.18033688011112042f

// ------- merged prep: 4 weight transposes + LN1, one launch -----------------
// blocks [0,6912): W[K][N] fp32 -> Wt[N][K] bf16, 32x32 tiles
// blocks [6912,8960): LN1 wave-per-row (4 rows/block) fp32 -> bf16
__global__ __launch_bounds__(256)
void prep_all(const float* __restrict__ W0, const float* __restrict__ W1,
              const float* __restrict__ W2, const float* __restrict__ W3,
              unsigned short* __restrict__ T0, unsigned short* __restrict__ T1,
              unsigned short* __restrict__ T2, unsigned short* __restrict__ T3,
              const float* __restrict__ x, const float* __restrict__ g,
              const float* __restrict__ beta, unsigned short* __restrict__ lnout)
{
    __shared__ float tile_s[32][33];
    const int bid = blockIdx.x;

    if (bid >= 6912) {
        // ---- LN1 job ----
        const int row  = (bid - 6912) * 4 + (threadIdx.x >> 6);
        const int lane = threadIdx.x & 63;
        const float* xr = x + (long)row * 768;
        float4 v[3];
        float s = 0.f, sq = 0.f;
#pragma unroll
        for (int j = 0; j < 3; ++j) {
            v[j] = *(const float4*)(xr + (lane + 64 * j) * 4);
            s  += (v[j].x + v[j].y) + (v[j].z + v[j].w);
            sq += (v[j].x * v[j].x + v[j].y * v[j].y) + (v[j].z * v[j].z + v[j].w * v[j].w);
        }
#pragma unroll
        for (int m = 1; m < 64; m <<= 1) {
            s  += __shfl_xor(s, m);
            sq += __shfl_xor(sq, m);
        }
        const float mean = s * (1.0f / 768.0f);
        const float var  = sq * (1.0f / 768.0f) - mean * mean;
        const float rstd = rsqrtf(var + 1e-5f);
        unsigned short* orow = lnout + (long)row * 768;
#pragma unroll
        for (int j = 0; j < 3; ++j) {
            const int c4 = (lane + 64 * j) * 4;
            const float4 gv = *(const float4*)(g + c4);
            const float4 bv = *(const float4*)(beta + c4);
            ushort4v o;
            o[0] = f2bf((v[j].x - mean) * rstd * gv.x + bv.x);
            o[1] = f2bf((v[j].y - mean) * rstd * gv.y + bv.y);
            o[2] = f2bf((v[j].z - mean) * rstd * gv.z + bv.z);
            o[3] = f2bf((v[j].w - mean) * rstd * gv.w + bv.w);
            *(ushort4v*)(orow + c4) = o;
        }
        return;
    }

    // ---- transpose job ----
    const float* W; unsigned short* Wt; int K, N, nx, tile;
    if (bid < 1728)      { W = W0; Wt = T0; K = 768;  N = 2304; nx = 72; tile = bid; }
    else if (bid < 2304) { W = W1; Wt = T1; K = 768;  N = 768;  nx = 24; tile = bid - 1728; }
    else if (bid < 4608) { W = W2; Wt = T2; K = 768;  N = 3072; nx = 96; tile = bid - 2304; }
    else                 { W = W3; Wt = T3; K = 3072; N = 768;  nx = 24; tile = bid - 4608; }
    const int n0 = (tile % nx) * 32, k0 = (tile / nx) * 32;
    const int tx = threadIdx.x & 31, ty = threadIdx.x >> 5;   // ty 0..7
#pragma unroll
    for (int j = 0; j < 4; ++j)
        tile_s[ty + j * 8][tx] = W[(long)(k0 + ty + j * 8) * N + n0 + tx];
    __syncthreads();
#pragma unroll
    for (int j = 0; j < 4; ++j)
        Wt[(long)(n0 + ty + j * 8) * K + k0 + tx] = f2bf(tile_s[tx][ty + j * 8]);
}

// ---------------- LayerNorm over bf16 input (row=768) -> bf16 ---------------
// wave-per-row, 4 rows/block; 12 elems/lane via 3 x ushort4 loads.
__global__ __launch_bounds__(256)
void ln_cast_bf16(const unsigned short* __restrict__ x, const float* __restrict__ g,
                  const float* __restrict__ beta, unsigned short* __restrict__ out)
{
    const int row  = blockIdx.x * 4 + (threadIdx.x >> 6);
    const int lane = threadIdx.x & 63;
    const unsigned short* xr = x + (long)row * 768;

    float v[12];
    float s = 0.f, sq = 0.f;
#pragma unroll
    for (int j = 0; j < 3; ++j) {
        ushort4v u = *(const ushort4v*)(xr + (lane + 64 * j) * 4);
#pragma unroll
        for (int e = 0; e < 4; ++e) {
            const float f = bf2f(u[e]);
            v[j * 4 + e] = f;
            s += f; sq += f * f;
        }
    }
#pragma unroll
    for (int m = 1; m < 64; m <<= 1) {
        s  += __shfl_xor(s, m);
        sq += __shfl_xor(sq, m);
    }
    const float mean = s * (1.0f / 768.0f);
    const float var  = sq * (1.0f / 768.0f) - mean * mean;
    const float rstd = rsqrtf(var + 1e-5f);

    unsigned short* orow = out + (long)row * 768;
#pragma unroll
    for (int j = 0; j < 3; ++j) {
        const int c4 = (lane + 64 * j) * 4;
        const float4 gv = *(const float4*)(g + c4);
        const float4 bv = *(const float4*)(beta + c4);
        ushort4v o;
        o[0] = f2bf((v[j * 4 + 0] - mean) * rstd * gv.x + bv.x);
        o[1] = f2bf((v[j * 4 + 1] - mean) * rstd * gv.y + bv.y);
        o[2] = f2bf((v[j * 4 + 2] - mean) * rstd * gv.z + bv.z);
        o[3] = f2bf((v[j * 4 + 3] - mean) * rstd * gv.w + bv.w);
        *(ushort4v*)(orow + c4) = o;
    }
}

// ---------------- 128x128-tile bf16 MFMA GEMM, templated epilogue -----------
// A [M][K] bf16 row-major, Bt [N][K] bf16 (B transposed), M=8192.
// EPI 0: qkv scatter (+bias) -> ob0=q[B,H,T,D] (pre-scaled by QSCALE),
//        ob1=k[B,H,T,D],
//        ob2=vT[B,H,D,T] with token order scrambled within 32-blocks
//        (pos = 8*((t>>2)&3) + 4*((t>>4)&1) + (t&3)) so attn PV fragments
//        read contiguous 16B. MFMA contracts slot-wise, so applying the same
//        permutation to P-slot packing and V keeps the math identical.
// EPI 2: +bias, gelu  -> ob0 bf16 [M][N]
template<int EPI>
__global__ __launch_bounds__(256)
void gemm128(const unsigned short* __restrict__ A,
             const unsigned short* __restrict__ Bt,
             const float* __restrict__ bias,
             unsigned short* __restrict__ ob0,
             unsigned short* __restrict__ ob1,
             unsigned short* __restrict__ ob2,
             int K, int N)
{
    const int wg = xcd_swizzle(gridDim.x);
    const int gY = gridDim.y;
    const int mt = wg / gY, nt = wg % gY;
    const int tid = threadIdx.x;
    const int w = tid >> 6, lane = tid & 63;
    const int l16 = lane & 15, lq = lane >> 4;
    const int wm = w >> 1, wn = w & 1;

    __shared__ unsigned short As[128 * 64];
    __shared__ unsigned short Bs[128 * 64];

    const floatx4 fzero = {0.f, 0.f, 0.f, 0.f};
    floatx4 acc[4][4];
#pragma unroll
    for (int i = 0; i < 4; ++i)
#pragma unroll
        for (int j = 0; j < 4; ++j) acc[i][j] = fzero;

    const char* Abyte = (const char*)A + (long)mt * 128 * K * 2;
    const char* Bbyte = (const char*)Bt + (long)nt * 128 * K * 2;
    const int KT = K >> 6;

    for (int kt = 0; kt < KT; ++kt) {
        const int kbyte = kt * 128;                    // 64 elems * 2B
#pragma unroll
        for (int r4 = 0; r4 < 4; ++r4) {
            int base = (w * 4 + r4) * 1024;
            int loff = base + lane * 16;
            int row  = loff >> 7;                      // 128B per row
            int scb  = (loff & 127) ^ ((row & 7) << 4);
            gload16(Abyte + (long)row * (K * 2) + kbyte + scb, (char*)As + base);
            gload16(Bbyte + (long)row * (K * 2) + kbyte + scb, (char*)Bs + base);
        }
        __syncthreads();
#pragma unroll
        for (int ks = 0; ks < 2; ++ks) {
            const int kb = ks * 64 + lq * 16;
            short8 af[4], bfr[4];
#pragma unroll
            for (int f = 0; f < 4; ++f) {
                int ar = wm * 64 + f * 16 + l16;
                af[f]  = *(const short8*)((const char*)As + ar * 128 + (kb ^ ((ar & 7) << 4)));
                int br = wn * 64 + f * 16 + l16;
                bfr[f] = *(const short8*)((const char*)Bs + br * 128 + (kb ^ ((br & 7) << 4)));
            }
#pragma unroll
            for (int i = 0; i < 4; ++i)
#pragma unroll
                for (int j = 0; j < 4; ++j)
                    acc[i][j] = __builtin_amdgcn_mfma_f32_16x16x32_bf16(af[i], bfr[j], acc[i][j], 0, 0, 0);
        }
        __syncthreads();
    }

    const int col0 = nt * 128 + wn * 64;
    const int row0 = mt * 128 + wm * 64;
#pragma unroll
    for (int j = 0; j < 4; ++j) {
        const int col = col0 + j * 16 + l16;
        const float bv = bias[col];
#pragma unroll
        for (int i = 0; i < 4; ++i) {
            const int rowb = row0 + i * 16 + lq * 4;   // 4 consecutive rows
            float v[4];
#pragma unroll
            for (int r = 0; r < 4; ++r) v[r] = acc[i][j][r] + bv;

            if (EPI == 0) {
                const int which = (col >= 1536) ? 2 : (col >= 768 ? 1 : 0);
                const int c = col - which * 768;
                const int hh = c >> 6, d = c & 63;
                const int bb = rowb >> 11;
                const int t  = rowb & 2047;
                if (which == 2) {
                    ushort4v pk;
#pragma unroll
                    for (int r = 0; r < 4; ++r) pk[r] = f2bf(v[r]);
                    const int tlo = t & 31;   // multiple of 4
                    const int tS  = (t & ~31) + ((tlo & 12) << 1) + ((tlo & 16) >> 2);
                    long vi = ((long)(bb * 12 + hh) * 64 + d) * 2048 + tS;
                    *(ushort4v*)(ob2 + vi) = pk;
                } else {
                    unsigned short* dst = (which == 0) ? ob0 : ob1;
                    const float qs = (which == 0) ? QSCALE : 1.0f;
                    long base = ((long)(bb * 12 + hh) * 2048 + t) * 64 + d;
#pragma unroll
                    for (int r = 0; r < 4; ++r) dst[base + (long)r * 64] = f2bf(v[r] * qs);
                }
            } else {  // EPI == 2
#pragma unroll
                for (int r = 0; r < 4; ++r) {
                    long idx = (long)(rowb + r) * N + col;
                    ob0[idx] = f2bf(gelu_f(v[r]));
                }
            }
        }
    }
}

// ---------------- 128x64-tile bf16 MFMA GEMM (narrow-N: proj / out) ---------
// EPI 0: +bias + fp32 resid -> bf16 obf   (attn sublayer: res1 = x + proj)
// EPI 1: +bias + bf16 resid -> fp32 of    (final: out = res1 + mlp)
template<int EPI>
__global__ __launch_bounds__(256)
void gemm_n64(const unsigned short* __restrict__ A,
              const unsigned short* __restrict__ Bt,
              const float* __restrict__ bias,
              const float* __restrict__ residF,
              const unsigned short* __restrict__ residB,
              unsigned short* __restrict__ obf,
              float* __restrict__ of,
              int K, int N)
{
    const int wg = xcd_swizzle(gridDim.x);
    const int gY = gridDim.y;
    const int mt = wg / gY, nt = wg % gY;
    const int tid = threadIdx.x;
    const int w = tid >> 6, lane = tid & 63;
    const int l16 = lane & 15, lq = lane >> 4;
    const int wm = w >> 1, wn = w & 1;

    __shared__ unsigned short As[128 * 64];
    __shared__ unsigned short Bs[64 * 64];

    const floatx4 fzero = {0.f, 0.f, 0.f, 0.f};
    floatx4 acc[4][2];
#pragma unroll
    for (int i = 0; i < 4; ++i)
#pragma unroll
        for (int j = 0; j < 2; ++j) acc[i][j] = fzero;

    const int K2 = K * 2;
    const char* Abyte = (const char*)A + (long)mt * 128 * K2;
    const char* Bbyte = (const char*)Bt + (long)nt * 64 * K2;
    const int KT = K >> 6;

    for (int kt = 0; kt < KT; ++kt) {
        const int kbyte = kt * 128;                    // 64 elems * 2B
#pragma unroll
        for (int r4 = 0; r4 < 4; ++r4) {
            int base = (w * 4 + r4) * 1024;
            int loff = base + lane * 16;
            int row  = loff >> 7;
            int scb  = (loff & 127) ^ ((row & 7) << 4);
            gload16(Abyte + (long)row * K2 + kbyte + scb, (char*)As + base);
        }
#pragma unroll
        for (int r2 = 0; r2 < 2; ++r2) {
            int base = (w * 2 + r2) * 1024;
            int loff = base + lane * 16;
            int row  = loff >> 7;
            int scb  = (loff & 127) ^ ((row & 7) << 4);
            gload16(Bbyte + (long)row * K2 + kbyte + scb, (char*)Bs + base);
        }
        __syncthreads();
#pragma unroll
        for (int ks = 0; ks < 2; ++ks) {
            const int kb = ks * 64 + lq * 16;
            short8 af[4], bfr[2];
#pragma unroll
            for (int f = 0; f < 4; ++f) {
                int ar = wm * 64 + f * 16 + l16;
                af[f] = *(const short8*)((const char*)As + ar * 128 + (kb ^ ((ar & 7) << 4)));
            }
#pragma unroll
            for (int f = 0; f < 2; ++f) {
                int br = wn * 32 + f * 16 + l16;
                bfr[f] = *(const short8*)((const char*)Bs + br * 128 + (kb ^ ((br & 7) << 4)));
            }
#pragma unroll
            for (int i = 0; i < 4; ++i)
#pragma unroll
                for (int j = 0; j < 2; ++j)
                    acc[i][j] = __builtin_amdgcn_mfma_f32_16x16x32_bf16(af[i], bfr[j], acc[i][j], 0, 0, 0);
        }
        __syncthreads();
    }

    const int col0 = nt * 64 + wn * 32;
    const int row0 = mt * 128 + wm * 64;
#pragma unroll
    for (int j = 0; j < 2; ++j) {
        const int col = col0 + j * 16 + l16;
        const float bv = bias[col];
#pragma unroll
        for (int i = 0; i < 4; ++i) {
            const int rowb = row0 + i * 16 + lq * 4;
#pragma unroll
            for (int r = 0; r < 4; ++r) {
                long idx = (long)(rowb + r) * N + col;
                if (EPI == 0)
                    obf[idx] = f2bf(acc[i][j][r] + bv + residF[idx]);
                else
                    of[idx] = acc[i][j][r] + bv + bf2f(residB[idx]);
            }
        }
    }
}

// ---------------- flash attention fwd: 8 waves, 128 q-rows per block --------
// q,k: bf16 [B*H, 2048, 64] (q pre-scaled); vt: bf16 [B*H, 64, 2048]
// (32-token scrambled); y: bf16 [B*T, 768]. r10-proven version (110.0 us).
__global__ __launch_bounds__(512)
void attn_fwd(const unsigned short* __restrict__ q,
              const unsigned short* __restrict__ k,
              const unsigned short* __restrict__ vt,
              const float* __restrict__ mask,
              unsigned short* __restrict__ y)
{
    const int qt = blockIdx.x;     // 0..15 (128 q rows each)
    const int bh = blockIdx.y;     // 0..47
    const int b = bh / 12, h = bh - b * 12;
    const int tid = threadIdx.x;   // 0..511
    const int w = tid >> 6, lane = tid & 63;
    const int l16 = lane & 15, lq = lane >> 4;

    __shared__ unsigned short Ks[128 * 64];
    __shared__ unsigned short Vs[64 * 128];
    __shared__ float madd[128];
    __shared__ int mq;

    if (tid == 0) mq = 0;
    __syncthreads();
    {
        const float* mrow = mask + (long)b * 2048 + tid * 4;
        int bad = 0;
#pragma unroll
        for (int j = 0; j < 4; ++j) bad |= (mrow[j] != 1.0f);
        if (bad) atomicOr(&mq, 1);
    }

    // Q fragments in registers (B operand of swapped QK^T)
    const unsigned short* qrow = q + ((long)bh * 2048 + qt * 128 + w * 16 + l16) * 64;
    const short8 qf0 = *(const short8*)(qrow + lq * 8);
    const short8 qf1 = *(const short8*)(qrow + 32 + lq * 8);

    // hoisted per-thread staging offsets (512 threads x 16B x 2 passes each)
    const char* kg = (const char*)(k + (long)bh * 2048 * 64);
    const char* vg = (const char*)(vt + (long)bh * 64 * 2048);
    int koff[2], voff[2], lb[2];
#pragma unroll
    for (int r2 = 0; r2 < 2; ++r2) {
        int loff = r2 * 8192 + tid * 16;          // 0..16383
        int rowK = loff >> 7;
        koff[r2] = rowK * 128 + ((loff & 127) ^ ((rowK & 7) << 4));
        int rowV = loff >> 8;
        voff[r2] = rowV * 4096 + ((loff & 255) ^ ((rowV & 7) << 4));
        lb[r2]   = loff;
    }

    __syncthreads();
    const bool usemask = (mq != 0);

    const floatx4 fzero = {0.f, 0.f, 0.f, 0.f};
    floatx4 accO[4];
#pragma unroll
    for (int n = 0; n < 4; ++n) accO[n] = fzero;
    float m2 = -1e30f, lsum = 0.f;

    for (int kt = 0; kt < 16; ++kt) {
        const char* kgt = kg + (long)kt * 16384;   // 128 rows * 128B
        const char* vgt = vg + kt * 256;           // 128 cols * 2B
#pragma unroll
        for (int r2 = 0; r2 < 2; ++r2) {
            gload16(kgt + koff[r2], (char*)Ks + lb[r2]);
            gload16(vgt + voff[r2], (char*)Vs + lb[r2]);
        }
        if (usemask && tid < 128)
            madd[tid] = (1.0f - mask[b * 2048 + kt * 128 + tid]) * (-10000.0f * 1.4426950408889634f);
        __syncthreads();

        // S^T = K Q^T : lane -> S[key=f*16+lq*4+j][q=l16]
        floatx4 st[8];
#pragma unroll
        for (int f = 0; f < 8; ++f) st[f] = fzero;
        __builtin_amdgcn_s_setprio(1);
#pragma unroll
        for (int f = 0; f < 8; ++f) {
            const int kr = f * 16 + l16;
            const int sw = (kr & 7) << 4;
            short8 ka0 = *(const short8*)((const char*)Ks + kr * 128 + ((lq * 16) ^ sw));
            short8 ka1 = *(const short8*)((const char*)Ks + kr * 128 + ((64 + lq * 16) ^ sw));
            st[f] = __builtin_amdgcn_mfma_f32_16x16x32_bf16(ka0, qf0, st[f], 0, 0, 0);
            st[f] = __builtin_amdgcn_mfma_f32_16x16x32_bf16(ka1, qf1, st[f], 0, 0, 0);
        }
        __builtin_amdgcn_s_setprio(0);

        if (usemask) {
#pragma unroll
            for (int f = 0; f < 8; ++f) {
                floatx4 md = *(const floatx4*)((const char*)madd + f * 64 + lq * 16);
                st[f] += md;
            }
        }

        // split S into float2 halves (packed-math friendly)
        float2v lo[8], hi[8];
#pragma unroll
        for (int f = 0; f < 8; ++f) {
            lo[f][0] = st[f][0]; lo[f][1] = st[f][1];
            hi[f][0] = st[f][2]; hi[f][1] = st[f][3];
        }

        // row max: packed pairwise tree + cross-lq reduce
        float2v mx = __builtin_elementwise_max(lo[0], hi[0]);
#pragma unroll
        for (int f = 1; f < 8; ++f)
            mx = __builtin_elementwise_max(mx, __builtin_elementwise_max(lo[f], hi[f]));
        float rm = fmaxf(mx[0], mx[1]);
        rm = fmaxf(rm, __shfl_xor(rm, 16));
        rm = fmaxf(rm, __shfl_xor(rm, 32));

        if (!__all(rm <= m2 + 8.0f)) {      // defer-max (T13, THR=8 exp2-domain)
            const float mn = fmaxf(m2, rm);
            const float corr = exp2f(m2 - mn);
            m2 = mn;
            lsum *= corr;
            floatx4 cv;
            cv[0] = __shfl(corr, lq * 4 + 0);
            cv[1] = __shfl(corr, lq * 4 + 1);
            cv[2] = __shfl(corr, lq * 4 + 2);
            cv[3] = __shfl(corr, lq * 4 + 3);
#pragma unroll
            for (int n = 0; n < 4; ++n) accO[n] *= cv;
        }

        // P = exp2(S - m2): packed subtract + packed accumulate, scalar exp2
        const float2v m2v = {m2, m2};
        float2v rs2 = {0.f, 0.f};
        unsigned pw[16];
#pragma unroll
        for (int f = 0; f < 8; ++f) {
            float2v d0 = lo[f] - m2v;
            float2v d1 = hi[f] - m2v;
            float2v e0, e1;
            e0[0] = exp2f(d0[0]); e0[1] = exp2f(d0[1]);
            e1[0] = exp2f(d1[0]); e1[1] = exp2f(d1[1]);
            rs2 += e0;
            rs2 += e1;
            pw[f * 2]     = cvtpk_bf16(e0[0], e0[1]);
            pw[f * 2 + 1] = cvtpk_bf16(e1[0], e1[1]);
        }
        float rs = rs2[0] + rs2[1];
        rs += __shfl_xor(rs, 16);
        rs += __shfl_xor(rs, 32);
        lsum += rs;

        // O += P V  (P packed lane-locally; V tokens pre-scrambled to match)
        __builtin_amdgcn_s_setprio(1);
#pragma unroll
        for (int c = 0; c < 4; ++c) {
            union { unsigned u[4]; short8 s8; } pu;
            pu.u[0] = pw[c * 4 + 0];
            pu.u[1] = pw[c * 4 + 1];
            pu.u[2] = pw[c * 4 + 2];
            pu.u[3] = pw[c * 4 + 3];
            const int kb2 = c * 64 + lq * 16;
#pragma unroll
            for (int n = 0; n < 4; ++n) {
                const int vr = n * 16 + l16;
                short8 vb = *(const short8*)((const char*)Vs + vr * 256 + (kb2 ^ ((vr & 7) << 4)));
                accO[n] = __builtin_amdgcn_mfma_f32_16x16x32_bf16(pu.s8, vb, accO[n], 0, 0, 0);
            }
        }
        __builtin_amdgcn_s_setprio(0);
        __syncthreads();
    }

    const float li = 1.0f / lsum;
    floatx4 lv;
    lv[0] = __shfl(li, lq * 4 + 0);
    lv[1] = __shfl(li, lq * 4 + 1);
    lv[2] = __shfl(li, lq * 4 + 2);
    lv[3] = __shfl(li, lq * 4 + 3);
    unsigned short* ybase = y + ((long)(b * 2048 + qt * 128 + w * 16 + lq * 4)) * 768 + h * 64;
#pragma unroll
    for (int r = 0; r < 4; ++r) {
        unsigned short* yrow = ybase + (long)r * 768;
#pragma unroll
        for (int n = 0; n < 4; ++n)
            yrow[n * 16 + l16] = f2bf(accO[n][r] * lv[r]);
    }
}

// ---------------------------------------------------------------------------
extern "C" void kernel_launch(void* const* d_in, const int* in_sizes, int n_in,
                              void* d_out, int out_size, void* d_ws, size_t ws_size,
                              hipStream_t stream)
{
    const float* x     = (const float*)d_in[0];
    const float* amask = (const float*)d_in[1];
    const float* ln1g  = (const float*)d_in[2];
    const float* ln1b  = (const float*)d_in[3];
    const float* ln2g  = (const float*)d_in[4];
    const float* ln2b  = (const float*)d_in[5];
    const float* Wattn = (const float*)d_in[6];
    const float* battn = (const float*)d_in[7];
    const float* Wproj = (const float*)d_in[8];
    const float* bproj = (const float*)d_in[9];
    const float* Wfc   = (const float*)d_in[10];
    const float* bfc   = (const float*)d_in[11];
    const float* Wout  = (const float*)d_in[12];
    const float* bout  = (const float*)d_in[13];
    float* out = (float*)d_out;

    char* ws = (char*)d_ws;
    unsigned short* wt_attn = (unsigned short*)ws;  ws += (long)2304 * 768 * 2;
    unsigned short* wt_proj = (unsigned short*)ws;  ws += (long)768 * 768 * 2;
    unsigned short* wt_fc   = (unsigned short*)ws;  ws += (long)3072 * 768 * 2;
    unsigned short* wt_out  = (unsigned short*)ws;  ws += (long)768 * 3072 * 2;
    unsigned short* hbuf    = (unsigned short*)ws;  ws += (long)8192 * 768 * 2;
    unsigned short* qbuf    = (unsigned short*)ws;  ws += (long)48 * 2048 * 64 * 2;
    unsigned short* kbuf    = (unsigned short*)ws;  ws += (long)48 * 2048 * 64 * 2;
    unsigned short* vtbuf   = (unsigned short*)ws;  ws += (long)48 * 2048 * 64 * 2;
    unsigned short* ybuf    = (unsigned short*)ws;  ws += (long)8192 * 768 * 2;
    unsigned short* hfc     = (unsigned short*)ws;  ws += (long)8192 * 3072 * 2;
    // res1 ALIASES qbuf (exactly equal size: 48*2048*64 == 8192*768 elems).
    // qbuf is dead after attn_fwd; res1 is written by gemm_n64<0> which runs
    // strictly after attn_fwd in stream order. Keeps total ws at the proven
    // 127.4 MB footprint (r13's extra 12.6 MB allocation overflowed ws_size
    // and intermittently corrupted neighboring allocations -> r15 failure).
    unsigned short* res1    = qbuf;

    prep_all<<<8960, 256, 0, stream>>>(Wattn, Wproj, Wfc, Wout,
                                       wt_attn, wt_proj, wt_fc, wt_out,
                                       x, ln1g, ln1b, hbuf);

    gemm128<0><<<dim3(64, 18), 256, 0, stream>>>(hbuf, wt_attn, battn,
                                                 qbuf, kbuf, vtbuf, 768, 2304);

    attn_fwd<<<dim3(16, 48), 512, 0, stream>>>(qbuf, kbuf, vtbuf, amask, ybuf);

    // res1 = bf16(x + proj(y))   [attn sublayer output, bf16 residual]
    gemm_n64<0><<<dim3(64, 12), 256, 0, stream>>>(ybuf, wt_proj, bproj,
                                                  x, nullptr, res1, nullptr, 768, 768);

    ln_cast_bf16<<<2048, 256, 0, stream>>>(res1, ln2g, ln2b, hbuf);

    gemm128<2><<<dim3(64, 24), 256, 0, stream>>>(hbuf, wt_fc, bfc,
                                                 hfc, nullptr, nullptr, 768, 3072);

    // out = res1 + mlp(hfc)   [fp32 final output]
    gemm_n64<1><<<dim3(64, 12), 256, 0, stream>>>(hfc, wt_out, bout,
                                                  nullptr, res1, nullptr, out, 3072, 768);
}